// Round 15
// baseline (194.529 us; speedup 1.0000x reference)
//
#include <hip/hip_runtime.h>
#include <hip/hip_bf16.h>

#define N_   8
#define C_   128
#define H_   96
#define W_   96
#define G_   8
#define GC_  16
#define HW_  (H_ * W_)       // 9216
#define CHW_ (C_ * HW_)      // 1179648
#define EPS_ 1e-5f
#define BLKS_PER_N_ 192      // k_front tiles per sample (24 h-tiles * 8 groups)
#define PW_  100             // padded plane width (96 + 2*2)
#define PPLANE_ (PW_ * PW_ * GC_)   // shorts per padded (n,g) plane = 160000
#define OMP2_ 256            // A2: 8 groups x 32 rows (27 live + 5 pad)

typedef short bf16x8 __attribute__((ext_vector_type(8)));
typedef float f32x4 __attribute__((ext_vector_type(4)));

#if __has_builtin(__builtin_amdgcn_fdot2_f32_bf16)
#define HAVE_DOT2_ 1
typedef __bf16 bf16x2 __attribute__((ext_vector_type(2)));
static __device__ __forceinline__ bf16x2 u2bf2(unsigned int u) {
  union { unsigned int i; bf16x2 v; } c;
  c.i = u;
  return c.v;
}
#else
#define HAVE_DOT2_ 0
#endif

static __device__ __forceinline__ unsigned short f2bf(float f) {
  unsigned int u = __float_as_uint(f);
  unsigned int r = (u + 0x7fffu + ((u >> 16) & 1u)) >> 16;
  return (unsigned short)r;
}
// Packed f32x2 -> bf16x2 via v_cvt_pk_bf16_f32 (1 instr, RTNE -- bit-identical
// to f2bf's manual rounding).
static __device__ __forceinline__ unsigned int pk_bf2(float lo, float hi) {
  __hip_bfloat162 h = __float22bfloat162_rn(make_float2(lo, hi));
  union { __hip_bfloat162 h; unsigned int u; } c;
  c.h = h;
  return c.u;
}
static __device__ __forceinline__ float lo_bf(unsigned int u) {
  return __uint_as_float(u << 16);
}
static __device__ __forceinline__ float hi_bf(unsigned int u) {
  return __uint_as_float(u & 0xffff0000u);
}

// Branch-free exact-GELU via Abramowitz-Stegun 7.1.26 erf (|err| <= 1.5e-7,
// far below the bf16 quantization already applied to x1).
static __device__ __forceinline__ float fast_gelu(float z) {
  float s = z * 0.70710678118654752f;
  float as = fabsf(s);
  float t = __builtin_amdgcn_rcpf(fmaf(0.3275911f, as, 1.0f));
  float e = __expf(-as * as);
  float inner = fmaf(fmaf(fmaf(fmaf(1.061405429f, t, -1.453152027f), t,
                               1.421413741f), t, -0.284496736f), t, 0.254829592f);
  float y = fmaf(-inner * t, e, 1.0f);          // erf(|s|)
  float erf_s = copysignf(y, s);
  float hz = 0.5f * z;
  return fmaf(hz, erf_s, hz);
}

// Load one input row (5 cols: w0-1 .. w0+3) for a channel pair.
// SAFE=true: row guaranteed in bounds (interior h-tiles) -> vy folds away.
template <bool SAFE>
static __device__ __forceinline__ void loadrow5t(float dst[2][5],
                                                 const float* __restrict__ xp0,
                                                 const float* __restrict__ xp1,
                                                 int hh, int w0) {
  bool vy = SAFE ? true : ((hh >= 0) & (hh < H_));
#pragma unroll
  for (int j = 0; j < 5; ++j) {
    int ww = w0 - 1 + j;
    bool v = vy & (ww >= 0) & (ww < W_);
    dst[0][j] = v ? xp0[hh * W_ + ww] : 0.0f;
    dst[1][j] = v ? xp1[hh * W_ + ww] : 0.0f;
  }
}

// Conv body for one 4-row tile (templated on vertical safety).
template <bool SAFE>
static __device__ __forceinline__ void conv_tile(const float* __restrict__ xp0,
                                                 const float* __restrict__ xp1,
                                                 const float wk[2][9],
                                                 const float bias[2],
                                                 int h0, int w0, int ty,
                                                 unsigned int* __restrict__ lds_a,
                                                 unsigned int* __restrict__ lds_c,
                                                 float& s, float& q) {
  float rr[3][2][5];
  loadrow5t<SAFE>(rr[0], xp0, xp1, h0 - 1, w0);
  loadrow5t<SAFE>(rr[1], xp0, xp1, h0,     w0);

#pragma unroll
  for (int r = 0; r < 4; ++r) {
    const int sA = r % 3;                // row h0+r-1
    const int sB = (r + 1) % 3;          // row h0+r
    const int sC = (r + 2) % 3;          // row h0+r+1
    loadrow5t<SAFE>(rr[sC], xp0, xp1, h0 + r + 1, w0);

#pragma unroll
    for (int j = 0; j < 3; ++j) {
      float acc0 = bias[0], acc1 = bias[1];
#pragma unroll
      for (int dx = 0; dx < 3; ++dx) {
        acc0 = fmaf(rr[sA][0][j + dx], wk[0][0 + dx], acc0);
        acc1 = fmaf(rr[sA][1][j + dx], wk[1][0 + dx], acc1);
        acc0 = fmaf(rr[sB][0][j + dx], wk[0][3 + dx], acc0);
        acc1 = fmaf(rr[sB][1][j + dx], wk[1][3 + dx], acc1);
        acc0 = fmaf(rr[sC][0][j + dx], wk[0][6 + dx], acc0);
        acc1 = fmaf(rr[sC][1][j + dx], wk[1][6 + dx], acc1);
      }
      float cen0 = rr[sB][0][j + 1];
      float cen1 = rr[sB][1][j + 1];
      s += acc0 + acc1;
      q = fmaf(acc0, acc0, q);
      q = fmaf(acc1, acc1, q);
      int pxl = r * 96 + w0 + j;          // 0..383
      lds_a[pxl * 9 + ty] = pk_bf2(acc0, acc1);
      lds_c[pxl * 9 + ty] = pk_bf2(cen0, cen1);
    }
  }
}

// ---------------------------------------------------------------------------
// K1 (R21): front conv + merged prep. Flat 1-D grid of 1536+192 blocks:
//  - blocks 0..1535: conv tiles (as before);
//  - blocks 1536..1663: permute+pad om_w -> A2 bf16 [8 groups x 32 rows x
//    128] (27 live rows + 5 zero) + biasp2[256];
//  - blocks 1664..1727: zero xgb plane borders.
// ---------------------------------------------------------------------------
__global__ __launch_bounds__(256) void k_front(const float* __restrict__ x,
                                               const float* __restrict__ dw_w,
                                               const float* __restrict__ dw_b,
                                               unsigned short* __restrict__ xgb,
                                               unsigned short* __restrict__ x1b,
                                               float2* __restrict__ partials,
                                               const float* __restrict__ om_w,
                                               const float* __restrict__ om_b,
                                               unsigned short* __restrict__ A2,
                                               float* __restrict__ biasp2) {
  int fb = blockIdx.x;
  int tid = threadIdx.x;

  if (fb >= N_ * BLKS_PER_N_) {
    int pb2 = fb - N_ * BLKS_PER_N_;      // 0..191
    if (pb2 < 128) {
      int idx = pb2 * 256 + tid;          // 0 .. 256*128-1
      int o = idx >> 7;
      int cix = idx & 127;
      int g = o >> 5;
      int k = o & 31;
      float v = (k < 27) ? om_w[(g * 27 + k) * C_ + cix] : 0.0f;
      A2[idx] = f2bf(v);
      if (cix == 0) biasp2[o] = (k < 27) ? om_b[g * 27 + k] : 0.0f;
    } else {
      int gid = (pb2 - 128) * 256 + tid;  // 64 blocks
      const int NBORD = 64 * 784;         // 50176 border px
      for (int id = gid; id < NBORD; id += 64 * 256) {
        int plane = id / 784;
        int r = id - plane * 784;
        int row, col;
        if (r < 400) {                    // rows 0,1,98,99 full width
          int qq = r / 100;
          row = (qq < 2) ? qq : qq + 96;
          col = r - qq * 100;
        } else {                          // rows 2..97, cols 0,1,98,99
          int r2 = r - 400;
          int qq = r2 >> 2;
          int c4 = r2 & 3;
          row = 2 + qq;
          col = (c4 < 2) ? c4 : c4 + 96;
        }
        uint4* dst = (uint4*)(xgb + (size_t)plane * PPLANE_ + (row * PW_ + col) * GC_);
        uint4 z = {0, 0, 0, 0};
        dst[0] = z;
        dst[1] = z;
      }
    }
    return;
  }

  __shared__ unsigned int lds_c[384 * 9];   // raw centers, packed bf16x2, pad 9
  __shared__ unsigned int lds_a[384 * 9];   // conv outputs, packed bf16x2
  __shared__ float ls[4], lq[4];

  int tx = tid & 31;             // 0..31 (px-column triple)
  int ty = tid >> 5;             // 0..7  (channel pair)
  int n   = fb / BLKS_PER_N_;
  int rem = fb - n * BLKS_PER_N_;
  int g   = rem / 24;
  int hb  = rem - g * 24;        // 0..23
  int h0 = hb * 4;
  int w0 = tx * 3;

  const int c0 = g * 16 + 2 * ty;
  float wk[2][9];
  const float* wp = dw_w + c0 * 9;
#pragma unroll
  for (int j = 0; j < 9; ++j) {
    wk[0][j] = wp[j];
    wk[1][j] = wp[9 + j];
  }
  float bias[2] = {dw_b[c0], dw_b[c0 + 1]};

  const float* xp0 = x + ((size_t)(n * C_ + c0)) * HW_;
  const float* xp1 = xp0 + HW_;

  float s = 0.0f, q = 0.0f;

  if (hb > 0 && hb < 23) {
    conv_tile<true>(xp0, xp1, wk, bias, h0, w0, ty, lds_a, lds_c, s, q);
  } else {
    conv_tile<false>(xp0, xp1, wk, bias, h0, w0, ty, lds_a, lds_c, s, q);
  }
  __syncthreads();

  // write-out: px-major, 32B per px per tile, fully coalesced per row
  for (int i = tid; i < 384; i += 256) {
    int row = i / 96;
    int col = i - row * 96;
    unsigned int wc[8], wa[8];
#pragma unroll
    for (int k = 0; k < 8; ++k) {
      wc[k] = lds_c[i * 9 + k];
      wa[k] = lds_a[i * 9 + k];
    }
    // padded group-planar raw x
    unsigned int* xg = (unsigned int*)xgb + (size_t)(n * G_ + g) * (PPLANE_ / 2)
                       + ((h0 + row + 2) * PW_ + (col + 2)) * 8;
    uint4 c01 = {wc[0], wc[1], wc[2], wc[3]};
    uint4 c23 = {wc[4], wc[5], wc[6], wc[7]};
    *(uint4*)xg = c01;
    *(uint4*)(xg + 4) = c23;
    // NHWC conv output (raw, pre-norm)
    int p = (h0 + row) * W_ + col;
    unsigned int* xb = (unsigned int*)x1b + ((size_t)n * HW_ + p) * 64 + g * 8;
    uint4 a01 = {wa[0], wa[1], wa[2], wa[3]};
    uint4 a23 = {wa[4], wa[5], wa[6], wa[7]};
    *(uint4*)xb = a01;
    *(uint4*)(xb + 4) = a23;
  }

  // block reduction of sum/sumsq
#pragma unroll
  for (int o = 32; o > 0; o >>= 1) {
    s += __shfl_down(s, o);
    q += __shfl_down(q, o);
  }
  int lane = tid & 63;
  int wv = tid >> 6;
  if (lane == 0) { ls[wv] = s; lq[wv] = q; }
  __syncthreads();
  if (tid == 0) {
    partials[fb] = make_float2(ls[0] + ls[1] + ls[2] + ls[3],
                               lq[0] + lq[1] + lq[2] + lq[3]);
  }
}

// ---------------------------------------------------------------------------
// K2 (R21): in-place LN+GELU over x1b (bf16 NHWC). Grid (144, 8); block =
// 64 px x 128 ch = 1024 uint4, 4/thread, channel set identical across the 4
// (ch = (tid*8)&127) so a8/b8 computed once. Stats reduction bit-identical
// to the old gemm's. Elementwise in-place: no cross-thread hazard.
// ---------------------------------------------------------------------------
__global__ __launch_bounds__(256) void k_gelu(unsigned int* __restrict__ x1b,
                                              const float2* __restrict__ partials,
                                              const float* __restrict__ gn_w,
                                              const float* __restrict__ gn_b) {
  __shared__ float ls[4], lq[4];
  int tid = threadIdx.x;
  int pb = blockIdx.x;
  int n = blockIdx.y;

  {
    float s = 0.0f, q = 0.0f;
    if (tid < BLKS_PER_N_) {
      float2 v = partials[n * BLKS_PER_N_ + tid];
      s = v.x;
      q = v.y;
    }
#pragma unroll
    for (int o = 32; o > 0; o >>= 1) {
      s += __shfl_down(s, o);
      q += __shfl_down(q, o);
    }
    int lane = tid & 63;
    int wv = tid >> 6;
    if (lane == 0) { ls[wv] = s; lq[wv] = q; }
  }
  __syncthreads();

  float sum = ls[0] + ls[1] + ls[2] + ls[3];
  float ssq = lq[0] + lq[1] + lq[2] + lq[3];
  const float inv = 1.0f / (float)CHW_;
  float mean = sum * inv;
  float var = ssq * inv - mean * mean;
  float rstd = rsqrtf(var + EPS_);
  int ch0 = (tid * 8) & 127;
  float a8[8], b8[8];
#pragma unroll
  for (int j = 0; j < 8; ++j) {
    float gw = gn_w[ch0 + j];
    float gb = gn_b[ch0 + j];
    a8[j] = rstd * gw;
    b8[j] = gb - mean * rstd * gw;
  }

  uint4* bp = (uint4*)x1b + (size_t)(n * HW_ + pb * 64) * 16;
#pragma unroll
  for (int jj = 0; jj < 4; ++jj) {
    uint4 raw = bp[tid + jj * 256];
    unsigned int d[4] = {raw.x, raw.y, raw.z, raw.w};
    unsigned int od[4];
#pragma unroll
    for (int t = 0; t < 4; ++t) {
      float v0 = lo_bf(d[t]);
      float v1 = hi_bf(d[t]);
      float z0 = fmaf(v0, a8[2 * t], b8[2 * t]);
      float z1 = fmaf(v1, a8[2 * t + 1], b8[2 * t + 1]);
      od[t] = pk_bf2(fast_gelu(z0), fast_gelu(z1));
    }
    uint4 packed = {od[0], od[1], od[2], od[3]};
    bp[tid + jj * 256] = packed;
  }
}

// ---------------------------------------------------------------------------
// K3 (R21): fused MFMA + deformable sampling, SAMPLER geometry (9216 blocks
// = 8n x 8g x 144 pb64, 4 waves). Phase A: om[32 o-rows][64 px] for THIS
// group only via 32 MFMAs (A2 rows g*32.., B = gelu'd x1 tile, loaded
// directly from global -- L2/L3 absorb the 8x group re-read). Output packed
// to om_lds[16][66] via the C/D fragment mapping (row-pair pad 66 avoids
// quad bank aliasing). Deletes the om2 HBM round-trip (59 MB) + one launch.
// Phase 1/2: identical to the proven k_sample (R17/R20), om reads from LDS.
// ---------------------------------------------------------------------------
__global__ __launch_bounds__(256) void k_mfma_sample(const unsigned short* __restrict__ x1g,
                                                     const unsigned short* __restrict__ A2,
                                                     const float* __restrict__ biasp2,
                                                     const unsigned short* __restrict__ xgb,
                                                     float* __restrict__ out) {
  __shared__ unsigned int om_lds[16 * 66];   // packed om dword rows
  __shared__ int4 s_wa[9 * 64];              // {w_col0 pair, w_col1 pair, byt_y0, byt_y1}

  int tid = threadIdx.x;
  int ord = blockIdx.x;
  int n = ord & 7;
  int t2 = ord >> 3;
  int g = t2 & 7;
  int pb = t2 >> 3;
  int p0 = pb * 64;

  // ---- Phase A: om for group g ----
  int wave = tid >> 6;           // px-tile 0..3
  int lane = tid & 63;
  int quad = lane >> 4;
  int l16 = lane & 15;

  const unsigned short* bsrc =
      x1g + ((size_t)(n * HW_ + p0 + wave * 16 + l16)) * C_ + quad * 8;
  bf16x8 bfrag[4];
#pragma unroll
  for (int kk = 0; kk < 4; ++kk)
    bfrag[kk] = *(const bf16x8*)(bsrc + kk * 32);

  int px = wave * 16 + l16;
#pragma unroll
  for (int ot2 = 0; ot2 < 2; ++ot2) {
    const unsigned short* asrc = A2 + (size_t)(g * 32 + ot2 * 16 + l16) * C_ + quad * 8;
    bf16x8 af[4];
#pragma unroll
    for (int kk = 0; kk < 4; ++kk)
      af[kk] = *(const bf16x8*)(asrc + kk * 32);
    f32x4 acc = {0.f, 0.f, 0.f, 0.f};
#pragma unroll
    for (int kk = 0; kk < 4; ++kk)
      acc = __builtin_amdgcn_mfma_f32_16x16x32_bf16(af[kk], bfrag[kk], acc, 0, 0, 0);
    int o0 = ot2 * 16 + quad * 4;          // even
    float4 bv = *(const float4*)(biasp2 + g * 32 + o0);
    int r2 = o0 >> 1;
    om_lds[r2 * 66 + px] = pk_bf2(acc[0] + bv.x, acc[1] + bv.y);
    om_lds[(r2 + 1) * 66 + px] = pk_bf2(acc[2] + bv.z, acc[3] + bv.w);
  }
  __syncthreads();

  // ---- Phase 1: sampling descriptors (om from LDS) ----
  int hb0 = p0 / W_;             // scalar (pb uniform)
  int wb0 = p0 - hb0 * W_;

  for (int j = tid; j < 576; j += 256) {
    int pt = j >> 6;
    int pxj = j & 63;
    int wsum = wb0 + pxj;
    int carry = wsum >= W_;
    int h = hb0 + carry;
    int w = wsum - (carry ? W_ : 0);
    unsigned int od = om_lds[pt * 66 + pxj];
    unsigned int md = om_lds[(9 + (pt >> 1)) * 66 + pxj];
    float offx = lo_bf(od);
    float offy = hi_bf(od);
    float m = (pt & 1) ? hi_bf(md) : lo_bf(md);
    float locy = (float)(h + pt / 3 - 1) + offy;
    float locx = (float)(w + pt % 3 - 1) + offx;
    float y0f = floorf(locy);
    float x0f = floorf(locx);
    float ly = locy - y0f;
    float lx = locx - x0f;
    int y0 = (int)y0f;
    int x0 = (int)x0f;
    y0 = min(max(y0, -2), 96);     // clamp into padded range; clamped rows are zero
    x0 = min(max(x0, -2), 96);
    float t0 = (1.0f - ly) * m;
    float t1 = ly * m;
    float u0 = 1.0f - lx;
    int4 wa;
    wa.x = (int)pk_bf2(t0 * u0, t1 * u0);        // x-col0: (y0 w, y1 w)
    wa.y = (int)pk_bf2(t0 * lx, t1 * lx);        // x-col1: (y0 w, y1 w)
    wa.z = ((y0 + 2) * PW_ + (x0 + 2)) * (GC_ * 2);  // BYTE offset, row y0
    wa.w = wa.z + PW_ * GC_ * 2;                     // row y1
    s_wa[j] = wa;
  }
  __syncthreads();

  // ---- Phase 2: gather + weighted accumulate (4 lanes/px) ----
  int px_l = tid >> 2;             // 0..63
  int sub = tid & 3;               // bit1 = x-col, bit0 = channel-chunk
  int rowhalf = sub >> 1;
  int chunk = sub & 1;
  int p = p0 + px_l;
  const char* xs = (const char*)(xgb + (size_t)(n * G_ + g) * PPLANE_) + sub * 16;

  float acc[8] = {0, 0, 0, 0, 0, 0, 0, 0};

#if HAVE_DOT2_
#define DOT9_(WA, R0, R1)                                                      \
  {                                                                            \
    unsigned int aw = (unsigned int)(rowhalf ? (WA).y : (WA).x);               \
    bf16x2 a2 = u2bf2(aw);                                                     \
    unsigned int d0[4] = {(R0).x, (R0).y, (R0).z, (R0).w};                     \
    unsigned int d1[4] = {(R1).x, (R1).y, (R1).z, (R1).w};                     \
    _Pragma("unroll")                                                          \
    for (int t = 0; t < 4; ++t) {                                              \
      unsigned int blo = __builtin_amdgcn_perm(d1[t], d0[t], 0x05040100u);     \
      unsigned int bhi = __builtin_amdgcn_perm(d1[t], d0[t], 0x07060302u);     \
      acc[2 * t]     = __builtin_amdgcn_fdot2_f32_bf16(a2, u2bf2(blo),         \
                                                       acc[2 * t], false);     \
      acc[2 * t + 1] = __builtin_amdgcn_fdot2_f32_bf16(a2, u2bf2(bhi),         \
                                                       acc[2 * t + 1], false); \
    }                                                                          \
  }
#else
#define DOT9_(WA, R0, R1)                                                      \
  {                                                                            \
    unsigned int aw = (unsigned int)(rowhalf ? (WA).y : (WA).x);               \
    float w0 = lo_bf(aw);                                                      \
    float w1 = hi_bf(aw);                                                      \
    unsigned int d0[4] = {(R0).x, (R0).y, (R0).z, (R0).w};                     \
    unsigned int d1[4] = {(R1).x, (R1).y, (R1).z, (R1).w};                     \
    _Pragma("unroll")                                                          \
    for (int t = 0; t < 4; ++t) {                                              \
      acc[2 * t]     = fmaf(w0, lo_bf(d0[t]), acc[2 * t]);                     \
      acc[2 * t + 1] = fmaf(w0, hi_bf(d0[t]), acc[2 * t + 1]);                 \
      acc[2 * t]     = fmaf(w1, lo_bf(d1[t]), acc[2 * t]);                     \
      acc[2 * t + 1] = fmaf(w1, hi_bf(d1[t]), acc[2 * t + 1]);                 \
    }                                                                          \
  }
#endif

#pragma unroll
  for (int grp = 0; grp < 3; ++grp) {
    int4 waA = s_wa[(grp * 3 + 0) * 64 + px_l];
    int4 waB = s_wa[(grp * 3 + 1) * 64 + px_l];
    int4 waC = s_wa[(grp * 3 + 2) * 64 + px_l];
    uint4 a0 = *(const uint4*)(xs + waA.z);
    uint4 a1 = *(const uint4*)(xs + waA.w);
    uint4 b0 = *(const uint4*)(xs + waB.z);
    uint4 b1 = *(const uint4*)(xs + waB.w);
    uint4 c0 = *(const uint4*)(xs + waC.z);
    uint4 c1 = *(const uint4*)(xs + waC.w);
    __builtin_amdgcn_sched_barrier(0);   // pin all 6 loads before compute
    DOT9_(waA, a0, a1);
    DOT9_(waB, b0, b1);
    DOT9_(waC, c0, c1);
  }
#undef DOT9_

  // fold the two x-cols (lanes sub and sub^2 hold the same 8 channels)
#pragma unroll
  for (int i = 0; i < 8; ++i) acc[i] += __shfl_xor(acc[i], 2);

  int ch = chunk * 8 + rowhalf * 4;
  float* op = out + ((size_t)(n * C_ + g * GC_ + ch)) * HW_ + p;
#pragma unroll
  for (int r = 0; r < 4; ++r) op[r * HW_] = acc[rowhalf * 4 + r];
}

// ---------------------------------------------------------------------------
extern "C" void kernel_launch(void* const* d_in, const int* in_sizes, int n_in,
                              void* d_out, int out_size, void* d_ws, size_t ws_size,
                              hipStream_t stream) {
  const float* x    = (const float*)d_in[0];
  const float* dw_w = (const float*)d_in[1];
  const float* dw_b = (const float*)d_in[2];
  const float* gn_w = (const float*)d_in[3];
  const float* gn_b = (const float*)d_in[4];
  const float* om_w = (const float*)d_in[5];
  const float* om_b = (const float*)d_in[6];
  float* out = (float*)d_out;

  // workspace layout (~40 MB; om2 eliminated)
  unsigned short* xgb = (unsigned short*)d_ws;                       // 64 * 160000 us (padded planes)
  unsigned short* x1b = xgb + (size_t)64 * PPLANE_;                  // 9437184 us (raw -> gelu'd in place)
  float2* partials = (float2*)(x1b + (size_t)N_ * CHW_);             // 1536 float2
  unsigned short* A2 = (unsigned short*)(partials + N_ * BLKS_PER_N_); // 256*128 us
  float* biasp2 = (float*)(A2 + (size_t)OMP2_ * C_);                 // 256 f

  k_front<<<N_ * BLKS_PER_N_ + 192, 256, 0, stream>>>(
      x, dw_w, dw_b, xgb, x1b, partials, om_w, om_b, A2, biasp2);
  k_gelu<<<dim3(HW_ / 64, N_), 256, 0, stream>>>(
      (unsigned int*)x1b, partials, gn_w, gn_b);
  k_mfma_sample<<<9216, 256, 0, stream>>>(x1b, A2, biasp2, xgb, out);
}

// Round 16
// 176.989 us; speedup vs baseline: 1.0991x; 1.0991x over previous
//
#include <hip/hip_runtime.h>
#include <hip/hip_bf16.h>

#define N_   8
#define C_   128
#define H_   96
#define W_   96
#define G_   8
#define GC_  16
#define HW_  (H_ * W_)       // 9216
#define CHW_ (C_ * HW_)      // 1179648
#define OM_  216
#define OMP_ 224             // padded: 8 groups x 28 rows (27 live + 1 pad)
#define OMROWS2_ 112         // packed dword rows per sample (224/2)
#define EPS_ 1e-5f
#define BLKS_PER_N_ 192      // k_front tiles per sample (24 h-tiles * 8 groups)
#define PW_  100             // padded plane width (96 + 2*2)
#define PPLANE_ (PW_ * PW_ * GC_)   // shorts per padded (n,g) plane = 160000

typedef short bf16x8 __attribute__((ext_vector_type(8)));
typedef float f32x4 __attribute__((ext_vector_type(4)));

#if __has_builtin(__builtin_amdgcn_fdot2_f32_bf16)
#define HAVE_DOT2_ 1
typedef __bf16 bf16x2 __attribute__((ext_vector_type(2)));
static __device__ __forceinline__ bf16x2 u2bf2(unsigned int u) {
  union { unsigned int i; bf16x2 v; } c;
  c.i = u;
  return c.v;
}
#else
#define HAVE_DOT2_ 0
#endif

static __device__ __forceinline__ unsigned short f2bf(float f) {
  unsigned int u = __float_as_uint(f);
  unsigned int r = (u + 0x7fffu + ((u >> 16) & 1u)) >> 16;
  return (unsigned short)r;
}
// Packed f32x2 -> bf16x2 via v_cvt_pk_bf16_f32 (1 instr, RTNE -- bit-identical
// to f2bf's manual rounding).
static __device__ __forceinline__ unsigned int pk_bf2(float lo, float hi) {
  __hip_bfloat162 h = __float22bfloat162_rn(make_float2(lo, hi));
  union { __hip_bfloat162 h; unsigned int u; } c;
  c.h = h;
  return c.u;
}
static __device__ __forceinline__ float lo_bf(unsigned int u) {
  return __uint_as_float(u << 16);
}
static __device__ __forceinline__ float hi_bf(unsigned int u) {
  return __uint_as_float(u & 0xffff0000u);
}

// Branch-free exact-GELU via Abramowitz-Stegun 7.1.26 erf (|err| <= 1.5e-7,
// far below the bf16 quantization already applied to x1).
static __device__ __forceinline__ float fast_gelu(float z) {
  float s = z * 0.70710678118654752f;
  float as = fabsf(s);
  float t = __builtin_amdgcn_rcpf(fmaf(0.3275911f, as, 1.0f));
  float e = __expf(-as * as);
  float inner = fmaf(fmaf(fmaf(fmaf(1.061405429f, t, -1.453152027f), t,
                               1.421413741f), t, -0.284496736f), t, 0.254829592f);
  float y = fmaf(-inner * t, e, 1.0f);          // erf(|s|)
  float erf_s = copysignf(y, s);
  float hz = 0.5f * z;
  return fmaf(hz, erf_s, hz);
}

// Load one input row (5 cols: w0-1 .. w0+3) for a channel pair.
// SAFE=true: row guaranteed in bounds (interior h-tiles) -> vy folds away.
template <bool SAFE>
static __device__ __forceinline__ void loadrow5t(float dst[2][5],
                                                 const float* __restrict__ xp0,
                                                 const float* __restrict__ xp1,
                                                 int hh, int w0) {
  bool vy = SAFE ? true : ((hh >= 0) & (hh < H_));
#pragma unroll
  for (int j = 0; j < 5; ++j) {
    int ww = w0 - 1 + j;
    bool v = vy & (ww >= 0) & (ww < W_);
    dst[0][j] = v ? xp0[hh * W_ + ww] : 0.0f;
    dst[1][j] = v ? xp1[hh * W_ + ww] : 0.0f;
  }
}

// Conv body for one 4-row tile (templated on vertical safety).
template <bool SAFE>
static __device__ __forceinline__ void conv_tile(const float* __restrict__ xp0,
                                                 const float* __restrict__ xp1,
                                                 const float wk[2][9],
                                                 const float bias[2],
                                                 int h0, int w0, int ty,
                                                 unsigned int* __restrict__ lds_a,
                                                 unsigned int* __restrict__ lds_c,
                                                 float& s, float& q) {
  float rr[3][2][5];
  loadrow5t<SAFE>(rr[0], xp0, xp1, h0 - 1, w0);
  loadrow5t<SAFE>(rr[1], xp0, xp1, h0,     w0);

#pragma unroll
  for (int r = 0; r < 4; ++r) {
    const int sA = r % 3;                // row h0+r-1
    const int sB = (r + 1) % 3;          // row h0+r
    const int sC = (r + 2) % 3;          // row h0+r+1
    loadrow5t<SAFE>(rr[sC], xp0, xp1, h0 + r + 1, w0);

#pragma unroll
    for (int j = 0; j < 3; ++j) {
      float acc0 = bias[0], acc1 = bias[1];
#pragma unroll
      for (int dx = 0; dx < 3; ++dx) {
        acc0 = fmaf(rr[sA][0][j + dx], wk[0][0 + dx], acc0);
        acc1 = fmaf(rr[sA][1][j + dx], wk[1][0 + dx], acc1);
        acc0 = fmaf(rr[sB][0][j + dx], wk[0][3 + dx], acc0);
        acc1 = fmaf(rr[sB][1][j + dx], wk[1][3 + dx], acc1);
        acc0 = fmaf(rr[sC][0][j + dx], wk[0][6 + dx], acc0);
        acc1 = fmaf(rr[sC][1][j + dx], wk[1][6 + dx], acc1);
      }
      float cen0 = rr[sB][0][j + 1];
      float cen1 = rr[sB][1][j + 1];
      s += acc0 + acc1;
      q = fmaf(acc0, acc0, q);
      q = fmaf(acc1, acc1, q);
      int pxl = r * 96 + w0 + j;          // 0..383
      lds_a[pxl * 9 + ty] = pk_bf2(acc0, acc1);
      lds_c[pxl * 9 + ty] = pk_bf2(cen0, cen1);
    }
  }
}

// ---------------------------------------------------------------------------
// K1: front conv + merged prep. Flat 1-D grid of 1536+192 blocks.
// Interior h-tiles (hb 1..22) take a SAFE conv body (vertical bounds check
// constant-folds away). Values bit-identical.
// ---------------------------------------------------------------------------
__global__ __launch_bounds__(256) void k_front(const float* __restrict__ x,
                                               const float* __restrict__ dw_w,
                                               const float* __restrict__ dw_b,
                                               unsigned short* __restrict__ xgb,
                                               unsigned short* __restrict__ x1b,
                                               float2* __restrict__ partials,
                                               const float* __restrict__ om_w,
                                               const float* __restrict__ om_b,
                                               unsigned short* __restrict__ A,
                                               float* __restrict__ biasp) {
  int fb = blockIdx.x;
  int tid = threadIdx.x;

  if (fb >= N_ * BLKS_PER_N_) {
    int pb2 = fb - N_ * BLKS_PER_N_;      // 0..191
    if (pb2 < 112) {
      int idx = pb2 * 256 + tid;          // 0 .. 224*128-1
      int o = idx >> 7;
      int cix = idx & 127;
      int g = o / 28;
      int k = o - g * 28;
      float v = (k < 27) ? om_w[(g * 27 + k) * C_ + cix] : 0.0f;
      A[idx] = f2bf(v);
      if (cix == 0) biasp[o] = (k < 27) ? om_b[g * 27 + k] : 0.0f;
    } else {
      int gid = (pb2 - 112) * 256 + tid;  // 0 .. 20479
      const int NBORD = 64 * 784;         // 50176 border px
      for (int id = gid; id < NBORD; id += 80 * 256) {
        int plane = id / 784;
        int r = id - plane * 784;
        int row, col;
        if (r < 400) {                    // rows 0,1,98,99 full width
          int qq = r / 100;
          row = (qq < 2) ? qq : qq + 96;
          col = r - qq * 100;
        } else {                          // rows 2..97, cols 0,1,98,99
          int r2 = r - 400;
          int qq = r2 >> 2;
          int c4 = r2 & 3;
          row = 2 + qq;
          col = (c4 < 2) ? c4 : c4 + 96;
        }
        uint4* dst = (uint4*)(xgb + (size_t)plane * PPLANE_ + (row * PW_ + col) * GC_);
        uint4 z = {0, 0, 0, 0};
        dst[0] = z;
        dst[1] = z;
      }
    }
    return;
  }

  __shared__ unsigned int lds_c[384 * 9];   // raw centers, packed bf16x2, pad 9
  __shared__ unsigned int lds_a[384 * 9];   // conv outputs, packed bf16x2
  __shared__ float ls[4], lq[4];

  int tx = tid & 31;             // 0..31 (px-column triple)
  int ty = tid >> 5;             // 0..7  (channel pair)
  int n   = fb / BLKS_PER_N_;
  int rem = fb - n * BLKS_PER_N_;
  int g   = rem / 24;
  int hb  = rem - g * 24;        // 0..23
  int h0 = hb * 4;
  int w0 = tx * 3;

  const int c0 = g * 16 + 2 * ty;
  float wk[2][9];
  const float* wp = dw_w + c0 * 9;
#pragma unroll
  for (int j = 0; j < 9; ++j) {
    wk[0][j] = wp[j];
    wk[1][j] = wp[9 + j];
  }
  float bias[2] = {dw_b[c0], dw_b[c0 + 1]};

  const float* xp0 = x + ((size_t)(n * C_ + c0)) * HW_;
  const float* xp1 = xp0 + HW_;

  float s = 0.0f, q = 0.0f;

  if (hb > 0 && hb < 23) {
    conv_tile<true>(xp0, xp1, wk, bias, h0, w0, ty, lds_a, lds_c, s, q);
  } else {
    conv_tile<false>(xp0, xp1, wk, bias, h0, w0, ty, lds_a, lds_c, s, q);
  }
  __syncthreads();

  // write-out: px-major, 32B per px per tile, fully coalesced per row
  for (int i = tid; i < 384; i += 256) {
    int row = i / 96;
    int col = i - row * 96;
    unsigned int wc[8], wa[8];
#pragma unroll
    for (int k = 0; k < 8; ++k) {
      wc[k] = lds_c[i * 9 + k];
      wa[k] = lds_a[i * 9 + k];
    }
    // padded group-planar raw x
    unsigned int* xg = (unsigned int*)xgb + (size_t)(n * G_ + g) * (PPLANE_ / 2)
                       + ((h0 + row + 2) * PW_ + (col + 2)) * 8;
    uint4 c01 = {wc[0], wc[1], wc[2], wc[3]};
    uint4 c23 = {wc[4], wc[5], wc[6], wc[7]};
    *(uint4*)xg = c01;
    *(uint4*)(xg + 4) = c23;
    // NHWC conv output
    int p = (h0 + row) * W_ + col;
    unsigned int* xb = (unsigned int*)x1b + ((size_t)n * HW_ + p) * 64 + g * 8;
    uint4 a01 = {wa[0], wa[1], wa[2], wa[3]};
    uint4 a23 = {wa[4], wa[5], wa[6], wa[7]};
    *(uint4*)xb = a01;
    *(uint4*)(xb + 4) = a23;
  }

  // block reduction of sum/sumsq
#pragma unroll
  for (int o = 32; o > 0; o >>= 1) {
    s += __shfl_down(s, o);
    q += __shfl_down(q, o);
  }
  int lane = tid & 63;
  int wv = tid >> 6;
  if (lane == 0) { ls[wv] = s; lq[wv] = q; }
  __syncthreads();
  if (tid == 0) {
    partials[fb] = make_float2(ls[0] + ls[1] + ls[2] + ls[3],
                               lq[0] + lq[1] + lq[2] + lq[3]);
  }
}

// A-fragment prefetch helper (4 x 16B loads for one o-tile).
static __device__ __forceinline__ void pref_af(bf16x8 (&af)[4],
                                               const unsigned short* __restrict__ A,
                                               int ot, int l16, int quad) {
  const unsigned short* Ap = A + (ot * 16 + l16) * C_ + quad * 8;
#pragma unroll
  for (int kk = 0; kk < 4; ++kk) af[kk] = *(const bf16x8*)(Ap + kk * 32);
}

// ---------------------------------------------------------------------------
// K4: MFMA GEMM with fused layernorm+GELU on the B operand + inline stats
// reduction; staging/gn/bias loads issued before the stats reduction;
// per-ot A-fragments double-buffered, sched_barrier-pinned. Grid (288, 8).
// NOTE (session findings): both fusion directions with the sampler were
// measured regressions (R18: -TLP/-coalescing; R21: +VALU/+latency). The
// om2 HBM round-trip (~9 us) is the cheaper structure.
// ---------------------------------------------------------------------------
__global__ __launch_bounds__(256) void k_gemm_mfma(const unsigned short* __restrict__ Bt,
                                                   const unsigned short* __restrict__ A,
                                                   const float* __restrict__ biasp,
                                                   const float2* __restrict__ partials,
                                                   const float* __restrict__ gn_w,
                                                   const float* __restrict__ gn_b,
                                                   unsigned int* __restrict__ om2) {
  __shared__ unsigned short Bl[32 * 136];
  __shared__ alignas(16) float s_bias[OMP_];
  __shared__ float ls[4], lq[4];
  int tid = threadIdx.x;
  int pb = blockIdx.x;
  int n = blockIdx.y;
  int p0 = pb * 32;

  // ---- issue all long-latency loads first ----
  const unsigned short* src = Bt + ((size_t)n * HW_ + p0) * C_;
  int col = tid & 15;
  int row0 = tid >> 4;                  // 0..15
  uint4 raw0 = *(const uint4*)(src + row0 * C_ + col * 8);
  uint4 raw1 = *(const uint4*)(src + (16 + row0) * C_ + col * 8);
  int cbase = col * 8;
  float gw8[8], gb8[8];
#pragma unroll
  for (int j = 0; j < 8; ++j) {
    gw8[j] = gn_w[cbase + j];
    gb8[j] = gn_b[cbase + j];
  }
  if (tid < OMP_ / 4) {
    ((float4*)s_bias)[tid] = ((const float4*)biasp)[tid];
  }
  __builtin_amdgcn_sched_barrier(0);    // pin the staging issues early

  // ---- stats reduction (its loads overlap the ones above) ----
  {
    float s = 0.0f, q = 0.0f;
    if (tid < BLKS_PER_N_) {
      float2 v = partials[n * BLKS_PER_N_ + tid];
      s = v.x;
      q = v.y;
    }
#pragma unroll
    for (int o = 32; o > 0; o >>= 1) {
      s += __shfl_down(s, o);
      q += __shfl_down(q, o);
    }
    int lane = tid & 63;
    int wv = tid >> 6;
    if (lane == 0) { ls[wv] = s; lq[wv] = q; }
  }
  __syncthreads();

  float sum = ls[0] + ls[1] + ls[2] + ls[3];
  float ssq = lq[0] + lq[1] + lq[2] + lq[3];
  const float inv = 1.0f / (float)CHW_;
  float mean = sum * inv;
  float var = ssq * inv - mean * mean;
  float rstd = rsqrtf(var + EPS_);
  float a8[8], b8[8];
#pragma unroll
  for (int j = 0; j < 8; ++j) {
    a8[j] = rstd * gw8[j];
    b8[j] = gb8[j] - mean * rstd * gw8[j];
  }

  // ---- LN+GELU on the pre-staged raws, write to LDS ----
  {
    uint4 raws[2] = {raw0, raw1};
#pragma unroll
    for (int i = 0; i < 2; ++i) {
      int row = row0 + i * 16;
      unsigned int d[4] = {raws[i].x, raws[i].y, raws[i].z, raws[i].w};
      unsigned int od[4];
#pragma unroll
      for (int t = 0; t < 4; ++t) {
        float v0 = lo_bf(d[t]);
        float v1 = hi_bf(d[t]);
        float z0 = fmaf(v0, a8[2 * t], b8[2 * t]);
        float z1 = fmaf(v1, a8[2 * t + 1], b8[2 * t + 1]);
        od[t] = pk_bf2(fast_gelu(z0), fast_gelu(z1));
      }
      uint4 packed = {od[0], od[1], od[2], od[3]};
      *(uint4*)(&Bl[row * 136 + col * 8]) = packed;
    }
  }
  __syncthreads();

  int wave = tid >> 6;
  int lane = tid & 63;
  int quad = lane >> 4;
  int l16 = lane & 15;
  int pixhalf = wave & 1;               // which 16-px half of the tile
  int othalf = wave >> 1;               // which half of the 14 o-tiles
  int prow = pixhalf * 16 + l16;

  bf16x8 bfrag[4];
#pragma unroll
  for (int kk = 0; kk < 4; ++kk)
    bfrag[kk] = *(const bf16x8*)(&Bl[prow * 136 + kk * 32 + quad * 8]);

  int p = p0 + prow;
  int base = othalf * 7;

#define COMP_(AF, OT)                                                          \
  {                                                                            \
    f32x4 acc = {0.f, 0.f, 0.f, 0.f};                                          \
    _Pragma("unroll")                                                          \
    for (int kk = 0; kk < 4; ++kk)                                             \
      acc = __builtin_amdgcn_mfma_f32_16x16x32_bf16(AF[kk], bfrag[kk], acc,    \
                                                    0, 0, 0);                  \
    int o0 = (OT) * 16 + quad * 4;                                             \
    float4 bv = *(const float4*)(&s_bias[o0]);                                 \
    unsigned int pk0 = pk_bf2(acc[0] + bv.x, acc[1] + bv.y);                   \
    unsigned int pk1 = pk_bf2(acc[2] + bv.z, acc[3] + bv.w);                   \
    unsigned int* Cp = om2 + ((size_t)n * OMROWS2_ + (o0 >> 1)) * HW_ + p;     \
    Cp[0] = pk0;                                                               \
    Cp[HW_] = pk1;                                                             \
  }
#define SB_ __builtin_amdgcn_sched_barrier(0)

  bf16x8 af0[4], af1[4];
  pref_af(af0, A, base + 0, l16, quad);
  pref_af(af1, A, base + 1, l16, quad);
  SB_;
  COMP_(af0, base + 0);
  pref_af(af0, A, base + 2, l16, quad);
  SB_;
  COMP_(af1, base + 1);
  pref_af(af1, A, base + 3, l16, quad);
  SB_;
  COMP_(af0, base + 2);
  pref_af(af0, A, base + 4, l16, quad);
  SB_;
  COMP_(af1, base + 3);
  pref_af(af1, A, base + 5, l16, quad);
  SB_;
  COMP_(af0, base + 4);
  pref_af(af0, A, base + 6, l16, quad);
  SB_;
  COMP_(af1, base + 5);
  COMP_(af0, base + 6);
#undef COMP_
#undef SB_
}

// ---------------------------------------------------------------------------
// K5: deformable bilinear sampling. s_wa stores BYTE offsets; per-lane base
// hoisted; pt loop in 3 groups of 3 (one latency wait per 3 pts, loads
// pinned by sched_barrier); carry-trick h,w. 4 lanes/px keeps the 64B row
// segments coalesced and TLP at 36864 waves.
// ---------------------------------------------------------------------------
__global__ __launch_bounds__(256) void k_sample(const unsigned short* __restrict__ xgb,
                                                const unsigned int* __restrict__ om2,
                                                float* __restrict__ out) {
  __shared__ int4 s_wa[9 * 64];   // {w_col0 pair, w_col1 pair, byt_y0, byt_y1}

  int tid = threadIdx.x;
  int ord = blockIdx.x;
  int n = ord & 7;
  int t2 = ord >> 3;
  int g = t2 & 7;
  int pb = t2 >> 3;
  int p0 = pb * 64;

  int hb0 = p0 / W_;             // scalar (pb uniform)
  int wb0 = p0 - hb0 * W_;

  const unsigned int* omb = om2 + ((size_t)n * OMROWS2_ + g * 14) * HW_ + p0;
  for (int j = tid; j < 576; j += 256) {
    int pt = j >> 6;
    int px = j & 63;
    int wsum = wb0 + px;
    int carry = wsum >= W_;
    int h = hb0 + carry;
    int w = wsum - (carry ? W_ : 0);
    unsigned int od = omb[pt * HW_ + px];
    float offx = lo_bf(od);
    float offy = hi_bf(od);
    unsigned int md = omb[(9 + (pt >> 1)) * HW_ + px];
    float m = (pt & 1) ? hi_bf(md) : lo_bf(md);
    float locy = (float)(h + pt / 3 - 1) + offy;
    float locx = (float)(w + pt % 3 - 1) + offx;
    float y0f = floorf(locy);
    float x0f = floorf(locx);
    float ly = locy - y0f;
    float lx = locx - x0f;
    int y0 = (int)y0f;
    int x0 = (int)x0f;
    y0 = min(max(y0, -2), 96);     // clamp into padded range; clamped rows are zero
    x0 = min(max(x0, -2), 96);
    float t0 = (1.0f - ly) * m;
    float t1 = ly * m;
    float u0 = 1.0f - lx;
    int4 wa;
    wa.x = (int)pk_bf2(t0 * u0, t1 * u0);        // x-col0: (y0 w, y1 w)
    wa.y = (int)pk_bf2(t0 * lx, t1 * lx);        // x-col1: (y0 w, y1 w)
    wa.z = ((y0 + 2) * PW_ + (x0 + 2)) * (GC_ * 2);  // BYTE offset, row y0
    wa.w = wa.z + PW_ * GC_ * 2;                     // row y1
    s_wa[j] = wa;
  }
  __syncthreads();

  int px_l = tid >> 2;             // 0..63
  int sub = tid & 3;               // bit1 = x-col, bit0 = channel-chunk
  int rowhalf = sub >> 1;
  int chunk = sub & 1;
  int p = p0 + px_l;
  const char* xs = (const char*)(xgb + (size_t)(n * G_ + g) * PPLANE_) + sub * 16;

  float acc[8] = {0, 0, 0, 0, 0, 0, 0, 0};

#if HAVE_DOT2_
#define DOT9_(WA, R0, R1)                                                      \
  {                                                                            \
    unsigned int aw = (unsigned int)(rowhalf ? (WA).y : (WA).x);               \
    bf16x2 a2 = u2bf2(aw);                                                     \
    unsigned int d0[4] = {(R0).x, (R0).y, (R0).z, (R0).w};                     \
    unsigned int d1[4] = {(R1).x, (R1).y, (R1).z, (R1).w};                     \
    _Pragma("unroll")                                                          \
    for (int t = 0; t < 4; ++t) {                                              \
      unsigned int blo = __builtin_amdgcn_perm(d1[t], d0[t], 0x05040100u);     \
      unsigned int bhi = __builtin_amdgcn_perm(d1[t], d0[t], 0x07060302u);     \
      acc[2 * t]     = __builtin_amdgcn_fdot2_f32_bf16(a2, u2bf2(blo),         \
                                                       acc[2 * t], false);     \
      acc[2 * t + 1] = __builtin_amdgcn_fdot2_f32_bf16(a2, u2bf2(bhi),         \
                                                       acc[2 * t + 1], false); \
    }                                                                          \
  }
#else
#define DOT9_(WA, R0, R1)                                                      \
  {                                                                            \
    unsigned int aw = (unsigned int)(rowhalf ? (WA).y : (WA).x);               \
    float w0 = lo_bf(aw);                                                      \
    float w1 = hi_bf(aw);                                                      \
    unsigned int d0[4] = {(R0).x, (R0).y, (R0).z, (R0).w};                     \
    unsigned int d1[4] = {(R1).x, (R1).y, (R1).z, (R1).w};                     \
    _Pragma("unroll")                                                          \
    for (int t = 0; t < 4; ++t) {                                              \
      acc[2 * t]     = fmaf(w0, lo_bf(d0[t]), acc[2 * t]);                     \
      acc[2 * t + 1] = fmaf(w0, hi_bf(d0[t]), acc[2 * t + 1]);                 \
      acc[2 * t]     = fmaf(w1, lo_bf(d1[t]), acc[2 * t]);                     \
      acc[2 * t + 1] = fmaf(w1, hi_bf(d1[t]), acc[2 * t + 1]);                 \
    }                                                                          \
  }
#endif

#pragma unroll
  for (int grp = 0; grp < 3; ++grp) {
    int4 waA = s_wa[(grp * 3 + 0) * 64 + px_l];
    int4 waB = s_wa[(grp * 3 + 1) * 64 + px_l];
    int4 waC = s_wa[(grp * 3 + 2) * 64 + px_l];
    uint4 a0 = *(const uint4*)(xs + waA.z);
    uint4 a1 = *(const uint4*)(xs + waA.w);
    uint4 b0 = *(const uint4*)(xs + waB.z);
    uint4 b1 = *(const uint4*)(xs + waB.w);
    uint4 c0 = *(const uint4*)(xs + waC.z);
    uint4 c1 = *(const uint4*)(xs + waC.w);
    __builtin_amdgcn_sched_barrier(0);   // pin all 6 loads before compute
    DOT9_(waA, a0, a1);
    DOT9_(waB, b0, b1);
    DOT9_(waC, c0, c1);
  }
#undef DOT9_

  // fold the two x-cols (lanes sub and sub^2 hold the same 8 channels)
#pragma unroll
  for (int i = 0; i < 8; ++i) acc[i] += __shfl_xor(acc[i], 2);

  int ch = chunk * 8 + rowhalf * 4;
  float* op = out + ((size_t)(n * C_ + g * GC_ + ch)) * HW_ + p;
#pragma unroll
  for (int r = 0; r < 4; ++r) op[r * HW_] = acc[rowhalf * 4 + r];
}

// ---------------------------------------------------------------------------
extern "C" void kernel_launch(void* const* d_in, const int* in_sizes, int n_in,
                              void* d_out, int out_size, void* d_ws, size_t ws_size,
                              hipStream_t stream) {
  const float* x    = (const float*)d_in[0];
  const float* dw_w = (const float*)d_in[1];
  const float* dw_b = (const float*)d_in[2];
  const float* gn_w = (const float*)d_in[3];
  const float* gn_b = (const float*)d_in[4];
  const float* om_w = (const float*)d_in[5];
  const float* om_b = (const float*)d_in[6];
  float* out = (float*)d_out;

  // workspace layout (~76 MB)
  unsigned short* xgb = (unsigned short*)d_ws;                       // 64 * 160000 us (padded planes)
  unsigned short* x1b = xgb + (size_t)64 * PPLANE_;                  // 9437184 us
  unsigned int* om2 = (unsigned int*)(x1b + (size_t)N_ * CHW_);      // 8*112*9216 u32
  float2* partials = (float2*)(om2 + (size_t)N_ * OMROWS2_ * HW_);   // 1536 float2
  unsigned short* Abf = (unsigned short*)(partials + N_ * BLKS_PER_N_);
  float* biasp = (float*)(Abf + OMP_ * C_);                          // 224 f

  k_front<<<N_ * BLKS_PER_N_ + 192, 256, 0, stream>>>(
      x, dw_w, dw_b, xgb, x1b, partials, om_w, om_b, Abf, biasp);
  k_gemm_mfma<<<dim3(HW_ / 32, N_), 256, 0, stream>>>(
      x1b, Abf, biasp, partials, gn_w, gn_b, om2);
  k_sample<<<9216, 256, 0, stream>>>(xgb, om2, out);
}

// Round 18
// 173.208 us; speedup vs baseline: 1.1231x; 1.0218x over previous
//
#include <hip/hip_runtime.h>
#include <hip/hip_bf16.h>

#define N_   8
#define C_   128
#define H_   96
#define W_   96
#define G_   8
#define GC_  16
#define HW_  (H_ * W_)       // 9216
#define CHW_ (C_ * HW_)      // 1179648
#define OM_  216
#define OMP_ 224             // padded: 8 groups x 28 rows (27 live + 1 pad)
#define OMROWS2_ 112         // packed dword rows per sample (224/2)
#define EPS_ 1e-5f
#define BLKS_PER_N_ 192      // k_front tiles per sample (24 h-tiles * 8 groups)
#define PW_  100             // padded plane width (96 + 2*2)
#define PPLANE_ (PW_ * PW_ * GC_)   // shorts per padded (n,g) plane = 160000

typedef short bf16x8 __attribute__((ext_vector_type(8)));
typedef float f32x4 __attribute__((ext_vector_type(4)));

#if __has_builtin(__builtin_amdgcn_fdot2_f32_bf16)
#define HAVE_DOT2_ 1
typedef __bf16 bf16x2 __attribute__((ext_vector_type(2)));
static __device__ __forceinline__ bf16x2 u2bf2(unsigned int u) {
  union { unsigned int i; bf16x2 v; } c;
  c.i = u;
  return c.v;
}
#else
#define HAVE_DOT2_ 0
#endif

static __device__ __forceinline__ unsigned short f2bf(float f) {
  unsigned int u = __float_as_uint(f);
  unsigned int r = (u + 0x7fffu + ((u >> 16) & 1u)) >> 16;
  return (unsigned short)r;
}
// Packed f32x2 -> bf16x2 via v_cvt_pk_bf16_f32 (1 instr, RTNE -- bit-identical
// to f2bf's manual rounding).
static __device__ __forceinline__ unsigned int pk_bf2(float lo, float hi) {
  __hip_bfloat162 h = __float22bfloat162_rn(make_float2(lo, hi));
  union { __hip_bfloat162 h; unsigned int u; } c;
  c.h = h;
  return c.u;
}
static __device__ __forceinline__ float lo_bf(unsigned int u) {
  return __uint_as_float(u << 16);
}
static __device__ __forceinline__ float hi_bf(unsigned int u) {
  return __uint_as_float(u & 0xffff0000u);
}

// Branch-free exact-GELU via Abramowitz-Stegun 7.1.26 erf (|err| <= 1.5e-7,
// far below the bf16 quantization already applied to x1).
static __device__ __forceinline__ float fast_gelu(float z) {
  float s = z * 0.70710678118654752f;
  float as = fabsf(s);
  float t = __builtin_amdgcn_rcpf(fmaf(0.3275911f, as, 1.0f));
  float e = __expf(-as * as);
  float inner = fmaf(fmaf(fmaf(fmaf(1.061405429f, t, -1.453152027f), t,
                               1.421413741f), t, -0.284496736f), t, 0.254829592f);
  float y = fmaf(-inner * t, e, 1.0f);          // erf(|s|)
  float erf_s = copysignf(y, s);
  float hz = 0.5f * z;
  return fmaf(hz, erf_s, hz);
}

// Load one input row (5 cols: w0-1 .. w0+3) for a channel pair.
// SAFE=true: row guaranteed in bounds (interior h-tiles) -> vy folds away.
template <bool SAFE>
static __device__ __forceinline__ void loadrow5t(float dst[2][5],
                                                 const float* __restrict__ xp0,
                                                 const float* __restrict__ xp1,
                                                 int hh, int w0) {
  bool vy = SAFE ? true : ((hh >= 0) & (hh < H_));
#pragma unroll
  for (int j = 0; j < 5; ++j) {
    int ww = w0 - 1 + j;
    bool v = vy & (ww >= 0) & (ww < W_);
    dst[0][j] = v ? xp0[hh * W_ + ww] : 0.0f;
    dst[1][j] = v ? xp1[hh * W_ + ww] : 0.0f;
  }
}

// Conv body for one 4-row tile (templated on vertical safety).
template <bool SAFE>
static __device__ __forceinline__ void conv_tile(const float* __restrict__ xp0,
                                                 const float* __restrict__ xp1,
                                                 const float wk[2][9],
                                                 const float bias[2],
                                                 int h0, int w0, int ty,
                                                 unsigned int* __restrict__ lds_a,
                                                 unsigned int* __restrict__ lds_c,
                                                 float& s, float& q) {
  float rr[3][2][5];
  loadrow5t<SAFE>(rr[0], xp0, xp1, h0 - 1, w0);
  loadrow5t<SAFE>(rr[1], xp0, xp1, h0,     w0);

#pragma unroll
  for (int r = 0; r < 4; ++r) {
    const int sA = r % 3;                // row h0+r-1
    const int sB = (r + 1) % 3;          // row h0+r
    const int sC = (r + 2) % 3;          // row h0+r+1
    loadrow5t<SAFE>(rr[sC], xp0, xp1, h0 + r + 1, w0);

#pragma unroll
    for (int j = 0; j < 3; ++j) {
      float acc0 = bias[0], acc1 = bias[1];
#pragma unroll
      for (int dx = 0; dx < 3; ++dx) {
        acc0 = fmaf(rr[sA][0][j + dx], wk[0][0 + dx], acc0);
        acc1 = fmaf(rr[sA][1][j + dx], wk[1][0 + dx], acc1);
        acc0 = fmaf(rr[sB][0][j + dx], wk[0][3 + dx], acc0);
        acc1 = fmaf(rr[sB][1][j + dx], wk[1][3 + dx], acc1);
        acc0 = fmaf(rr[sC][0][j + dx], wk[0][6 + dx], acc0);
        acc1 = fmaf(rr[sC][1][j + dx], wk[1][6 + dx], acc1);
      }
      float cen0 = rr[sB][0][j + 1];
      float cen1 = rr[sB][1][j + 1];
      s += acc0 + acc1;
      q = fmaf(acc0, acc0, q);
      q = fmaf(acc1, acc1, q);
      int pxl = r * 96 + w0 + j;          // 0..383
      lds_a[pxl * 9 + ty] = pk_bf2(acc0, acc1);
      lds_c[pxl * 9 + ty] = pk_bf2(cen0, cen1);
    }
  }
}

// ---------------------------------------------------------------------------
// K1: front conv + merged prep. Flat 1-D grid of 1536+192 blocks.
// Interior h-tiles (hb 1..22) take a SAFE conv body (vertical bounds check
// constant-folds away). Values bit-identical.
// ---------------------------------------------------------------------------
__global__ __launch_bounds__(256) void k_front(const float* __restrict__ x,
                                               const float* __restrict__ dw_w,
                                               const float* __restrict__ dw_b,
                                               unsigned short* __restrict__ xgb,
                                               unsigned short* __restrict__ x1b,
                                               float2* __restrict__ partials,
                                               const float* __restrict__ om_w,
                                               const float* __restrict__ om_b,
                                               unsigned short* __restrict__ A,
                                               float* __restrict__ biasp) {
  int fb = blockIdx.x;
  int tid = threadIdx.x;

  if (fb >= N_ * BLKS_PER_N_) {
    int pb2 = fb - N_ * BLKS_PER_N_;      // 0..191
    if (pb2 < 112) {
      int idx = pb2 * 256 + tid;          // 0 .. 224*128-1
      int o = idx >> 7;
      int cix = idx & 127;
      int g = o / 28;
      int k = o - g * 28;
      float v = (k < 27) ? om_w[(g * 27 + k) * C_ + cix] : 0.0f;
      A[idx] = f2bf(v);
      if (cix == 0) biasp[o] = (k < 27) ? om_b[g * 27 + k] : 0.0f;
    } else {
      int gid = (pb2 - 112) * 256 + tid;  // 0 .. 20479
      const int NBORD = 64 * 784;         // 50176 border px
      for (int id = gid; id < NBORD; id += 80 * 256) {
        int plane = id / 784;
        int r = id - plane * 784;
        int row, col;
        if (r < 400) {                    // rows 0,1,98,99 full width
          int qq = r / 100;
          row = (qq < 2) ? qq : qq + 96;
          col = r - qq * 100;
        } else {                          // rows 2..97, cols 0,1,98,99
          int r2 = r - 400;
          int qq = r2 >> 2;
          int c4 = r2 & 3;
          row = 2 + qq;
          col = (c4 < 2) ? c4 : c4 + 96;
        }
        uint4* dst = (uint4*)(xgb + (size_t)plane * PPLANE_ + (row * PW_ + col) * GC_);
        uint4 z = {0, 0, 0, 0};
        dst[0] = z;
        dst[1] = z;
      }
    }
    return;
  }

  __shared__ unsigned int lds_c[384 * 9];   // raw centers, packed bf16x2, pad 9
  __shared__ unsigned int lds_a[384 * 9];   // conv outputs, packed bf16x2
  __shared__ float ls[4], lq[4];

  int tx = tid & 31;             // 0..31 (px-column triple)
  int ty = tid >> 5;             // 0..7  (channel pair)
  int n   = fb / BLKS_PER_N_;
  int rem = fb - n * BLKS_PER_N_;
  int g   = rem / 24;
  int hb  = rem - g * 24;        // 0..23
  int h0 = hb * 4;
  int w0 = tx * 3;

  const int c0 = g * 16 + 2 * ty;
  float wk[2][9];
  const float* wp = dw_w + c0 * 9;
#pragma unroll
  for (int j = 0; j < 9; ++j) {
    wk[0][j] = wp[j];
    wk[1][j] = wp[9 + j];
  }
  float bias[2] = {dw_b[c0], dw_b[c0 + 1]};

  const float* xp0 = x + ((size_t)(n * C_ + c0)) * HW_;
  const float* xp1 = xp0 + HW_;

  float s = 0.0f, q = 0.0f;

  if (hb > 0 && hb < 23) {
    conv_tile<true>(xp0, xp1, wk, bias, h0, w0, ty, lds_a, lds_c, s, q);
  } else {
    conv_tile<false>(xp0, xp1, wk, bias, h0, w0, ty, lds_a, lds_c, s, q);
  }
  __syncthreads();

  // write-out: px-major, 32B per px per tile, fully coalesced per row
  for (int i = tid; i < 384; i += 256) {
    int row = i / 96;
    int col = i - row * 96;
    unsigned int wc[8], wa[8];
#pragma unroll
    for (int k = 0; k < 8; ++k) {
      wc[k] = lds_c[i * 9 + k];
      wa[k] = lds_a[i * 9 + k];
    }
    // padded group-planar raw x
    unsigned int* xg = (unsigned int*)xgb + (size_t)(n * G_ + g) * (PPLANE_ / 2)
                       + ((h0 + row + 2) * PW_ + (col + 2)) * 8;
    uint4 c01 = {wc[0], wc[1], wc[2], wc[3]};
    uint4 c23 = {wc[4], wc[5], wc[6], wc[7]};
    *(uint4*)xg = c01;
    *(uint4*)(xg + 4) = c23;
    // NHWC conv output
    int p = (h0 + row) * W_ + col;
    unsigned int* xb = (unsigned int*)x1b + ((size_t)n * HW_ + p) * 64 + g * 8;
    uint4 a01 = {wa[0], wa[1], wa[2], wa[3]};
    uint4 a23 = {wa[4], wa[5], wa[6], wa[7]};
    *(uint4*)xb = a01;
    *(uint4*)(xb + 4) = a23;
  }

  // block reduction of sum/sumsq
#pragma unroll
  for (int o = 32; o > 0; o >>= 1) {
    s += __shfl_down(s, o);
    q += __shfl_down(q, o);
  }
  int lane = tid & 63;
  int wv = tid >> 6;
  if (lane == 0) { ls[wv] = s; lq[wv] = q; }
  __syncthreads();
  if (tid == 0) {
    partials[fb] = make_float2(ls[0] + ls[1] + ls[2] + ls[3],
                               lq[0] + lq[1] + lq[2] + lq[3]);
  }
}

// A-fragment prefetch helper (4 x 16B loads for one o-tile).
static __device__ __forceinline__ void pref_af(bf16x8 (&af)[4],
                                               const unsigned short* __restrict__ A,
                                               int ot, int l16, int quad) {
  const unsigned short* Ap = A + (ot * 16 + l16) * C_ + quad * 8;
#pragma unroll
  for (int kk = 0; kk < 4; ++kk) af[kk] = *(const bf16x8*)(Ap + kk * 32);
}

// ---------------------------------------------------------------------------
// K4: MFMA GEMM with fused layernorm+GELU on the B operand + inline stats
// reduction; staging/gn/bias loads issued before the stats reduction;
// per-ot A-fragment chain with sched_barrier separators. Grid (288, 8).
// SESSION FINDINGS (measured): both fusion directions with the sampler
// regressed (R18 -TLP/-coalescing; R21 +VALU/+latency) -- the om2 HBM
// round-trip is the cheaper structure. hipcc re-sinks source-level prefetch
// regardless of program order / launch-bounds / sched_barrier (VGPR stayed
// 40 across all three); inline-asm loads crashed (R23, register-pending
// hazard) -- the remaining ~10 us in this kernel needs hand-assembled
// pipelining beyond safe iteration here.
// ---------------------------------------------------------------------------
__global__ __launch_bounds__(256) void k_gemm_mfma(const unsigned short* __restrict__ Bt,
                                                   const unsigned short* __restrict__ A,
                                                   const float* __restrict__ biasp,
                                                   const float2* __restrict__ partials,
                                                   const float* __restrict__ gn_w,
                                                   const float* __restrict__ gn_b,
                                                   unsigned int* __restrict__ om2) {
  __shared__ unsigned short Bl[32 * 136];
  __shared__ alignas(16) float s_bias[OMP_];
  __shared__ float ls[4], lq[4];
  int tid = threadIdx.x;
  int pb = blockIdx.x;
  int n = blockIdx.y;
  int p0 = pb * 32;

  // ---- issue all long-latency loads first ----
  const unsigned short* src = Bt + ((size_t)n * HW_ + p0) * C_;
  int col = tid & 15;
  int row0 = tid >> 4;                  // 0..15
  uint4 raw0 = *(const uint4*)(src + row0 * C_ + col * 8);
  uint4 raw1 = *(const uint4*)(src + (16 + row0) * C_ + col * 8);
  int cbase = col * 8;
  float gw8[8], gb8[8];
#pragma unroll
  for (int j = 0; j < 8; ++j) {
    gw8[j] = gn_w[cbase + j];
    gb8[j] = gn_b[cbase + j];
  }
  if (tid < OMP_ / 4) {
    ((float4*)s_bias)[tid] = ((const float4*)biasp)[tid];
  }
  __builtin_amdgcn_sched_barrier(0);    // pin the staging issues early

  // ---- stats reduction (its loads overlap the ones above) ----
  {
    float s = 0.0f, q = 0.0f;
    if (tid < BLKS_PER_N_) {
      float2 v = partials[n * BLKS_PER_N_ + tid];
      s = v.x;
      q = v.y;
    }
#pragma unroll
    for (int o = 32; o > 0; o >>= 1) {
      s += __shfl_down(s, o);
      q += __shfl_down(q, o);
    }
    int lane = tid & 63;
    int wv = tid >> 6;
    if (lane == 0) { ls[wv] = s; lq[wv] = q; }
  }
  __syncthreads();

  float sum = ls[0] + ls[1] + ls[2] + ls[3];
  float ssq = lq[0] + lq[1] + lq[2] + lq[3];
  const float inv = 1.0f / (float)CHW_;
  float mean = sum * inv;
  float var = ssq * inv - mean * mean;
  float rstd = rsqrtf(var + EPS_);
  float a8[8], b8[8];
#pragma unroll
  for (int j = 0; j < 8; ++j) {
    a8[j] = rstd * gw8[j];
    b8[j] = gb8[j] - mean * rstd * gw8[j];
  }

  // ---- LN+GELU on the pre-staged raws, write to LDS ----
  {
    uint4 raws[2] = {raw0, raw1};
#pragma unroll
    for (int i = 0; i < 2; ++i) {
      int row = row0 + i * 16;
      unsigned int d[4] = {raws[i].x, raws[i].y, raws[i].z, raws[i].w};
      unsigned int od[4];
#pragma unroll
      for (int t = 0; t < 4; ++t) {
        float v0 = lo_bf(d[t]);
        float v1 = hi_bf(d[t]);
        float z0 = fmaf(v0, a8[2 * t], b8[2 * t]);
        float z1 = fmaf(v1, a8[2 * t + 1], b8[2 * t + 1]);
        od[t] = pk_bf2(fast_gelu(z0), fast_gelu(z1));
      }
      uint4 packed = {od[0], od[1], od[2], od[3]};
      *(uint4*)(&Bl[row * 136 + col * 8]) = packed;
    }
  }
  __syncthreads();

  int wave = tid >> 6;
  int lane = tid & 63;
  int quad = lane >> 4;
  int l16 = lane & 15;
  int pixhalf = wave & 1;               // which 16-px half of the tile
  int othalf = wave >> 1;               // which half of the 14 o-tiles
  int prow = pixhalf * 16 + l16;

  bf16x8 bfrag[4];
#pragma unroll
  for (int kk = 0; kk < 4; ++kk)
    bfrag[kk] = *(const bf16x8*)(&Bl[prow * 136 + kk * 32 + quad * 8]);

  int p = p0 + prow;
  int base = othalf * 7;

#define COMP_(AF, OT)                                                          \
  {                                                                            \
    f32x4 acc = {0.f, 0.f, 0.f, 0.f};                                          \
    _Pragma("unroll")                                                          \
    for (int kk = 0; kk < 4; ++kk)                                             \
      acc = __builtin_amdgcn_mfma_f32_16x16x32_bf16(AF[kk], bfrag[kk], acc,    \
                                                    0, 0, 0);                  \
    int o0 = (OT) * 16 + quad * 4;                                             \
    float4 bv = *(const float4*)(&s_bias[o0]);                                 \
    unsigned int pk0 = pk_bf2(acc[0] + bv.x, acc[1] + bv.y);                   \
    unsigned int pk1 = pk_bf2(acc[2] + bv.z, acc[3] + bv.w);                   \
    unsigned int* Cp = om2 + ((size_t)n * OMROWS2_ + (o0 >> 1)) * HW_ + p;     \
    Cp[0] = pk0;                                                               \
    Cp[HW_] = pk1;                                                             \
  }
#define SB_ __builtin_amdgcn_sched_barrier(0)

  bf16x8 af0[4], af1[4];
  pref_af(af0, A, base + 0, l16, quad);
  pref_af(af1, A, base + 1, l16, quad);
  SB_;
  COMP_(af0, base + 0);
  pref_af(af0, A, base + 2, l16, quad);
  SB_;
  COMP_(af1, base + 1);
  pref_af(af1, A, base + 3, l16, quad);
  SB_;
  COMP_(af0, base + 2);
  pref_af(af0, A, base + 4, l16, quad);
  SB_;
  COMP_(af1, base + 3);
  pref_af(af1, A, base + 5, l16, quad);
  SB_;
  COMP_(af0, base + 4);
  pref_af(af0, A, base + 6, l16, quad);
  SB_;
  COMP_(af1, base + 5);
  COMP_(af0, base + 6);
#undef COMP_
#undef SB_
}

// ---------------------------------------------------------------------------
// K5: deformable bilinear sampling. s_wa stores BYTE offsets; per-lane base
// hoisted; pt loop in 3 groups of 3 (one latency wait per 3 pts, loads
// pinned by sched_barrier); carry-trick h,w. 4 lanes/px keeps the 64B row
// segments coalesced and TLP at 36864 waves.
// ---------------------------------------------------------------------------
__global__ __launch_bounds__(256) void k_sample(const unsigned short* __restrict__ xgb,
                                                const unsigned int* __restrict__ om2,
                                                float* __restrict__ out) {
  __shared__ int4 s_wa[9 * 64];   // {w_col0 pair, w_col1 pair, byt_y0, byt_y1}

  int tid = threadIdx.x;
  int ord = blockIdx.x;
  int n = ord & 7;
  int t2 = ord >> 3;
  int g = t2 & 7;
  int pb = t2 >> 3;
  int p0 = pb * 64;

  int hb0 = p0 / W_;             // scalar (pb uniform)
  int wb0 = p0 - hb0 * W_;

  const unsigned int* omb = om2 + ((size_t)n * OMROWS2_ + g * 14) * HW_ + p0;
  for (int j = tid; j < 576; j += 256) {
    int pt = j >> 6;
    int px = j & 63;
    int wsum = wb0 + px;
    int carry = wsum >= W_;
    int h = hb0 + carry;
    int w = wsum - (carry ? W_ : 0);
    unsigned int od = omb[pt * HW_ + px];
    float offx = lo_bf(od);
    float offy = hi_bf(od);
    unsigned int md = omb[(9 + (pt >> 1)) * HW_ + px];
    float m = (pt & 1) ? hi_bf(md) : lo_bf(md);
    float locy = (float)(h + pt / 3 - 1) + offy;
    float locx = (float)(w + pt % 3 - 1) + offx;
    float y0f = floorf(locy);
    float x0f = floorf(locx);
    float ly = locy - y0f;
    float lx = locx - x0f;
    int y0 = (int)y0f;
    int x0 = (int)x0f;
    y0 = min(max(y0, -2), 96);     // clamp into padded range; clamped rows are zero
    x0 = min(max(x0, -2), 96);
    float t0 = (1.0f - ly) * m;
    float t1 = ly * m;
    float u0 = 1.0f - lx;
    int4 wa;
    wa.x = (int)pk_bf2(t0 * u0, t1 * u0);        // x-col0: (y0 w, y1 w)
    wa.y = (int)pk_bf2(t0 * lx, t1 * lx);        // x-col1: (y0 w, y1 w)
    wa.z = ((y0 + 2) * PW_ + (x0 + 2)) * (GC_ * 2);  // BYTE offset, row y0
    wa.w = wa.z + PW_ * GC_ * 2;                     // row y1
    s_wa[j] = wa;
  }
  __syncthreads();

  int px_l = tid >> 2;             // 0..63
  int sub = tid & 3;               // bit1 = x-col, bit0 = channel-chunk
  int rowhalf = sub >> 1;
  int chunk = sub & 1;
  int p = p0 + px_l;
  const char* xs = (const char*)(xgb + (size_t)(n * G_ + g) * PPLANE_) + sub * 16;

  float acc[8] = {0, 0, 0, 0, 0, 0, 0, 0};

#if HAVE_DOT2_
#define DOT9_(WA, R0, R1)                                                      \
  {                                                                            \
    unsigned int aw = (unsigned int)(rowhalf ? (WA).y : (WA).x);               \
    bf16x2 a2 = u2bf2(aw);                                                     \
    unsigned int d0[4] = {(R0).x, (R0).y, (R0).z, (R0).w};                     \
    unsigned int d1[4] = {(R1).x, (R1).y, (R1).z, (R1).w};                     \
    _Pragma("unroll")                                                          \
    for (int t = 0; t < 4; ++t) {                                              \
      unsigned int blo = __builtin_amdgcn_perm(d1[t], d0[t], 0x05040100u);     \
      unsigned int bhi = __builtin_amdgcn_perm(d1[t], d0[t], 0x07060302u);     \
      acc[2 * t]     = __builtin_amdgcn_fdot2_f32_bf16(a2, u2bf2(blo),         \
                                                       acc[2 * t], false);     \
      acc[2 * t + 1] = __builtin_amdgcn_fdot2_f32_bf16(a2, u2bf2(bhi),         \
                                                       acc[2 * t + 1], false); \
    }                                                                          \
  }
#else
#define DOT9_(WA, R0, R1)                                                      \
  {                                                                            \
    unsigned int aw = (unsigned int)(rowhalf ? (WA).y : (WA).x);               \
    float w0 = lo_bf(aw);                                                      \
    float w1 = hi_bf(aw);                                                      \
    unsigned int d0[4] = {(R0).x, (R0).y, (R0).z, (R0).w};                     \
    unsigned int d1[4] = {(R1).x, (R1).y, (R1).z, (R1).w};                     \
    _Pragma("unroll")                                                          \
    for (int t = 0; t < 4; ++t) {                                              \
      acc[2 * t]     = fmaf(w0, lo_bf(d0[t]), acc[2 * t]);                     \
      acc[2 * t + 1] = fmaf(w0, hi_bf(d0[t]), acc[2 * t + 1]);                 \
      acc[2 * t]     = fmaf(w1, lo_bf(d1[t]), acc[2 * t]);                     \
      acc[2 * t + 1] = fmaf(w1, hi_bf(d1[t]), acc[2 * t + 1]);                 \
    }                                                                          \
  }
#endif

#pragma unroll
  for (int grp = 0; grp < 3; ++grp) {
    int4 waA = s_wa[(grp * 3 + 0) * 64 + px_l];
    int4 waB = s_wa[(grp * 3 + 1) * 64 + px_l];
    int4 waC = s_wa[(grp * 3 + 2) * 64 + px_l];
    uint4 a0 = *(const uint4*)(xs + waA.z);
    uint4 a1 = *(const uint4*)(xs + waA.w);
    uint4 b0 = *(const uint4*)(xs + waB.z);
    uint4 b1 = *(const uint4*)(xs + waB.w);
    uint4 c0 = *(const uint4*)(xs + waC.z);
    uint4 c1 = *(const uint4*)(xs + waC.w);
    __builtin_amdgcn_sched_barrier(0);   // pin all 6 loads before compute
    DOT9_(waA, a0, a1);
    DOT9_(waB, b0, b1);
    DOT9_(waC, c0, c1);
  }
#undef DOT9_

  // fold the two x-cols (lanes sub and sub^2 hold the same 8 channels)
#pragma unroll
  for (int i = 0; i < 8; ++i) acc[i] += __shfl_xor(acc[i], 2);

  int ch = chunk * 8 + rowhalf * 4;
  float* op = out + ((size_t)(n * C_ + g * GC_ + ch)) * HW_ + p;
#pragma unroll
  for (int r = 0; r < 4; ++r) op[r * HW_] = acc[rowhalf * 4 + r];
}

// ---------------------------------------------------------------------------
extern "C" void kernel_launch(void* const* d_in, const int* in_sizes, int n_in,
                              void* d_out, int out_size, void* d_ws, size_t ws_size,
                              hipStream_t stream) {
  const float* x    = (const float*)d_in[0];
  const float* dw_w = (const float*)d_in[1];
  const float* dw_b = (const float*)d_in[2];
  const float* gn_w = (const float*)d_in[3];
  const float* gn_b = (const float*)d_in[4];
  const float* om_w = (const float*)d_in[5];
  const float* om_b = (const float*)d_in[6];
  float* out = (float*)d_out;

  // workspace layout (~76 MB)
  unsigned short* xgb = (unsigned short*)d_ws;                       // 64 * 160000 us (padded planes)
  unsigned short* x1b = xgb + (size_t)64 * PPLANE_;                  // 9437184 us
  unsigned int* om2 = (unsigned int*)(x1b + (size_t)N_ * CHW_);      // 8*112*9216 u32
  float2* partials = (float2*)(om2 + (size_t)N_ * OMROWS2_ * HW_);   // 1536 float2
  unsigned short* Abf = (unsigned short*)(partials + N_ * BLKS_PER_N_);
  float* biasp = (float*)(Abf + OMP_ * C_);                          // 224 f

  k_front<<<N_ * BLKS_PER_N_ + 192, 256, 0, stream>>>(
      x, dw_w, dw_b, xgb, x1b, partials, om_w, om_b, Abf, biasp);
  k_gemm_mfma<<<dim3(HW_ / 32, N_), 256, 0, stream>>>(
      x1b, Abf, biasp, partials, gn_w, gn_b, om2);
  k_sample<<<9216, 256, 0, stream>>>(xgb, om2, out);
}